// Round 9
// baseline (1198.008 us; speedup 1.0000x reference)
//
#include <hip/hip_runtime.h>
#include <hip/hip_fp16.h>

#define D128 128
#define X19_STRIDE 768            // xs1 (384) + xs2 (384) fp16 elems per node

// ---------- scales[n] = {rsqrt(deg), rsqrt(1+log(deg))} ----------
__global__ void k_scales(const float* __restrict__ deg, float* __restrict__ scales, int N) {
  int n = blockIdx.x * blockDim.x + threadIdx.x;
  if (n >= N) return;
  float dg = deg[n];
  scales[2 * n]     = rsqrtf(dg);
  scales[2 * n + 1] = rsqrtf(1.0f + logf(dg));
}

// ---------- CSR build ----------
__global__ void k_hist(const int* __restrict__ row, int* __restrict__ cnt, int M) {
  int i = blockIdx.x * blockDim.x + threadIdx.x;
  if (i < M) atomicAdd(&cnt[row[i]], 1);
}

// single-block exclusive scan of cnt[0..n) -> off[0..n], also cursor[i]=off[i]
__global__ void k_scan(const int* __restrict__ cnt, int* __restrict__ off,
                       int* __restrict__ cursor, int n) {
  __shared__ int warp_sums[16];
  int carry = 0;
  int lane = threadIdx.x & 63;
  int wid  = threadIdx.x >> 6;
  for (int base = 0; base < n; base += 1024) {
    int i = base + (int)threadIdx.x;
    int v = (i < n) ? cnt[i] : 0;
    int s = v;
    #pragma unroll
    for (int d = 1; d < 64; d <<= 1) {
      int t = __shfl_up(s, d);
      if (lane >= d) s += t;
    }
    if (lane == 63) warp_sums[wid] = s;
    __syncthreads();
    if (threadIdx.x < 16) {
      int ws = warp_sums[threadIdx.x];
      #pragma unroll
      for (int d = 1; d < 16; d <<= 1) {
        int t = __shfl_up(ws, d);
        if ((int)threadIdx.x >= d) ws += t;
      }
      warp_sums[threadIdx.x] = ws;
    }
    __syncthreads();
    int excl = (s - v) + (wid > 0 ? warp_sums[wid - 1] : 0) + carry;
    if (i < n) { off[i] = excl; cursor[i] = excl; }
    carry += warp_sums[15];
    __syncthreads();
  }
  if (threadIdx.x == 0) off[n] = carry;
}

__global__ void k_scatter(const int* __restrict__ row, const int* __restrict__ col,
                          int* __restrict__ cursor, int* __restrict__ csr_col, int M) {
  int i = blockIdx.x * blockDim.x + threadIdx.x;
  if (i < M) {
    int r = row[i];
    int pos = atomicAdd(&cursor[r], 1);
    csr_col[pos] = col[i];
  }
}

// ---------- hop 1: xs1[r] = (1/deg[r]) * sum_c [x_sig[c] | x_sig[c]*s1(c) | x_sig[c]*s2(c)]
__global__ void __launch_bounds__(D128)
k_spmm1(const float* __restrict__ x_sig, const float* __restrict__ scales,
        __half* __restrict__ X19,
        const int* __restrict__ off, const int* __restrict__ csr_col,
        const float* __restrict__ deg) {
  int r = blockIdx.x;
  int d = threadIdx.x;
  __shared__ int scol[D128];
  int start = off[r], end = off[r + 1];
  float a0 = 0.f, a1 = 0.f, a2 = 0.f;
  for (int b = start; b < end; b += D128) {
    int len = min(end - b, D128);
    if (d < len) scol[d] = csr_col[b + d];
    __syncthreads();
    for (int j = 0; j < len; ++j) {
      int c = scol[j];
      float v  = x_sig[(size_t)c * D128 + d];
      float s1 = scales[2 * c];
      float s2 = scales[2 * c + 1];
      a0 += v;
      a1 += v * s1;
      a2 += v * s2;
    }
    __syncthreads();
  }
  float dr = 1.0f / deg[r];
  size_t o = (size_t)r * X19_STRIDE;
  X19[o + d]       = __float2half(a0 * dr);
  X19[o + 128 + d] = __float2half(a1 * dr);
  X19[o + 256 + d] = __float2half(a2 * dr);
}

// ---------- hop 2: xs2[r] = (1/deg[r]) * sum_c xs1[c] - xs0[r]
__global__ void __launch_bounds__(384)
k_spmm2(const float* __restrict__ x_sig, const float* __restrict__ scales,
        __half* __restrict__ X19,
        const int* __restrict__ off, const int* __restrict__ csr_col,
        const float* __restrict__ deg) {
  int r = blockIdx.x;
  int tid = threadIdx.x;            // 0..383 over xs1 slice
  __shared__ int scol[384];
  int start = off[r], end = off[r + 1];
  float acc = 0.f;
  for (int b = start; b < end; b += 384) {
    int len = min(end - b, 384);
    if (tid < len) scol[tid] = csr_col[b + tid];
    __syncthreads();
    for (int j = 0; j < len; ++j) {
      acc += __half2float(X19[(size_t)scol[j] * X19_STRIDE + tid]);
    }
    __syncthreads();
  }
  float dr = 1.0f / deg[r];
  int k = tid >> 7, dd = tid & 127;
  float xv = x_sig[(size_t)r * D128 + dd];
  float sk = (k == 0) ? 1.0f : ((k == 1) ? scales[2 * r] : scales[2 * r + 1]);
  X19[(size_t)r * X19_STRIDE + 384 + tid] = __float2half(acc * dr - xv * sk);
}

// ---------- edge gram: out[e] = flat(G + G^T), G = A B^T (9x128 rows), fp32 out ----------
__global__ void __launch_bounds__(D128)
k_edge(const float* __restrict__ x_sig, const float* __restrict__ scales,
       const __half* __restrict__ X19, const int* __restrict__ edge,
       float* __restrict__ out, int E) {
  int e = blockIdx.x;
  int tid = threadIdx.x;            // 0..127
  __shared__ float As[9 * 129];
  __shared__ float Bs[9 * 129];
  __shared__ float Gs[81];
  int u = edge[e];
  int v = edge[E + e];
  {
    float xu = x_sig[(size_t)u * D128 + tid];
    float s1 = scales[2 * u], s2 = scales[2 * u + 1];
    As[0 * 129 + tid] = xu;
    As[1 * 129 + tid] = xu * s1;
    As[2 * 129 + tid] = xu * s2;
    const __half* xp = X19 + (size_t)u * X19_STRIDE + tid;
    #pragma unroll
    for (int k = 0; k < 6; ++k) As[(3 + k) * 129 + tid] = __half2float(xp[k * 128]);
  }
  {
    float xv = x_sig[(size_t)v * D128 + tid];
    float s1 = scales[2 * v], s2 = scales[2 * v + 1];
    Bs[0 * 129 + tid] = xv;
    Bs[1 * 129 + tid] = xv * s1;
    Bs[2 * 129 + tid] = xv * s2;
    const __half* xp = X19 + (size_t)v * X19_STRIDE + tid;
    #pragma unroll
    for (int k = 0; k < 6; ++k) Bs[(3 + k) * 129 + tid] = __half2float(xp[k * 128]);
  }
  __syncthreads();
  if (tid < 81) {
    int k = tid % 9, l = tid / 9;
    const float* a = As + k * 129;
    const float* b = Bs + l * 129;
    float acc = 0.0f;
    #pragma unroll 8
    for (int d = 0; d < 128; ++d) acc += a[d] * b[d];
    Gs[k * 9 + l] = acc;
  }
  __syncthreads();
  if (tid < 81) {
    int k = tid / 9, l = tid % 9;
    out[(size_t)e * 81 + tid] = Gs[tid] + Gs[l * 9 + k];
  }
}

extern "C" void kernel_launch(void* const* d_in, const int* in_sizes, int n_in,
                              void* d_out, int out_size, void* d_ws, size_t ws_size,
                              hipStream_t stream) {
  const int*   edge    = (const int*)d_in[0];
  const int*   adj_row = (const int*)d_in[1];
  const int*   adj_col = (const int*)d_in[2];
  const float* deg     = (const float*)d_in[3];
  const float* x_sig   = (const float*)d_in[4];
  float* out = (float*)d_out;   // reference output dtype is float32

  const int E = in_sizes[0] / 2;
  const int M = in_sizes[1];
  const int N = in_sizes[3];

  // workspace layout: X19 (fp16), scales (f32), off/cursor/csr_col (i32)
  size_t x19_elems = (size_t)N * X19_STRIDE;                      // fp16
  size_t need = x19_elems * 2
              + (2 * (size_t)N) * 4                               // scales
              + ((size_t)(N + 1) + (size_t)N + (size_t)M) * 4;    // off, cursor, csr_col
  if (ws_size < need) return;  // diagnostic: all-zero output => absmax ~2.03125

  __half* X19   = (__half*)d_ws;
  float* scales = (float*)(X19 + x19_elems);
  int* off      = (int*)(scales + 2 * (size_t)N);
  int* cursor   = off + (N + 1);
  int* csr_col  = cursor + N;

  hipMemsetAsync(cursor, 0, (size_t)N * sizeof(int), stream);

  k_scales<<<(N + 255) / 256, 256, 0, stream>>>(deg, scales, N);
  k_hist<<<(M + 255) / 256, 256, 0, stream>>>(adj_row, cursor, M);
  k_scan<<<1, 1024, 0, stream>>>(cursor, off, cursor, N);
  k_scatter<<<(M + 255) / 256, 256, 0, stream>>>(adj_row, adj_col, cursor, csr_col, M);

  k_spmm1<<<N, D128, 0, stream>>>(x_sig, scales, X19, off, csr_col, deg);
  k_spmm2<<<N, 384, 0, stream>>>(x_sig, scales, X19, off, csr_col, deg);

  k_edge<<<E, D128, 0, stream>>>(x_sig, scales, X19, edge, out, E);
}

// Round 12
// 856.625 us; speedup vs baseline: 1.3985x; 1.3985x over previous
//
#include <hip/hip_runtime.h>
#include <hip/hip_fp16.h>

#define D128 128
#define X19_STRIDE 768            // xs1 (384) + xs2 (384) fp16 elems per node

typedef __attribute__((ext_vector_type(8))) _Float16 f16x8;
typedef __attribute__((ext_vector_type(4))) float    f32x4;

// ---------- scales[n] = {rsqrt(deg), rsqrt(1+log(deg))} ----------
__global__ void k_scales(const float* __restrict__ deg, float* __restrict__ scales, int N) {
  int n = blockIdx.x * blockDim.x + threadIdx.x;
  if (n >= N) return;
  float dg = deg[n];
  scales[2 * n]     = rsqrtf(dg);
  scales[2 * n + 1] = rsqrtf(1.0f + logf(dg));
}

// ---------- CSR build ----------
__global__ void k_hist(const int* __restrict__ row, int* __restrict__ cnt, int M) {
  int i = blockIdx.x * blockDim.x + threadIdx.x;
  if (i < M) atomicAdd(&cnt[row[i]], 1);
}

// single-block exclusive scan of cnt[0..n) -> off[0..n], also cursor[i]=off[i]
__global__ void k_scan(const int* __restrict__ cnt, int* __restrict__ off,
                       int* __restrict__ cursor, int n) {
  __shared__ int warp_sums[16];
  int carry = 0;
  int lane = threadIdx.x & 63;
  int wid  = threadIdx.x >> 6;
  for (int base = 0; base < n; base += 1024) {
    int i = base + (int)threadIdx.x;
    int v = (i < n) ? cnt[i] : 0;
    int s = v;
    #pragma unroll
    for (int d = 1; d < 64; d <<= 1) {
      int t = __shfl_up(s, d);
      if (lane >= d) s += t;
    }
    if (lane == 63) warp_sums[wid] = s;
    __syncthreads();
    if (threadIdx.x < 16) {
      int ws = warp_sums[threadIdx.x];
      #pragma unroll
      for (int d = 1; d < 16; d <<= 1) {
        int t = __shfl_up(ws, d);
        if ((int)threadIdx.x >= d) ws += t;
      }
      warp_sums[threadIdx.x] = ws;
    }
    __syncthreads();
    int excl = (s - v) + (wid > 0 ? warp_sums[wid - 1] : 0) + carry;
    if (i < n) { off[i] = excl; cursor[i] = excl; }
    carry += warp_sums[15];
    __syncthreads();
  }
  if (threadIdx.x == 0) off[n] = carry;
}

__global__ void k_scatter(const int* __restrict__ row, const int* __restrict__ col,
                          int* __restrict__ cursor, int* __restrict__ csr_col, int M) {
  int i = blockIdx.x * blockDim.x + threadIdx.x;
  if (i < M) {
    int r = row[i];
    int pos = atomicAdd(&cursor[r], 1);
    csr_col[pos] = col[i];
  }
}

// ---------- hop 1: xs1[r] = (1/deg[r]) * sum_c [x_sig[c] | x_sig[c]*s1(c) | x_sig[c]*s2(c)]
__global__ void __launch_bounds__(D128)
k_spmm1(const float* __restrict__ x_sig, const float* __restrict__ scales,
        __half* __restrict__ X19,
        const int* __restrict__ off, const int* __restrict__ csr_col,
        const float* __restrict__ deg) {
  int r = blockIdx.x;
  int d = threadIdx.x;
  __shared__ int scol[D128];
  int start = off[r], end = off[r + 1];
  float a0 = 0.f, a1 = 0.f, a2 = 0.f;
  for (int b = start; b < end; b += D128) {
    int len = min(end - b, D128);
    if (d < len) scol[d] = csr_col[b + d];
    __syncthreads();
    for (int j = 0; j < len; ++j) {
      int c = scol[j];
      float v  = x_sig[(size_t)c * D128 + d];
      float s1 = scales[2 * c];
      float s2 = scales[2 * c + 1];
      a0 += v;
      a1 += v * s1;
      a2 += v * s2;
    }
    __syncthreads();
  }
  float dr = 1.0f / deg[r];
  size_t o = (size_t)r * X19_STRIDE;
  X19[o + d]       = __float2half(a0 * dr);
  X19[o + 128 + d] = __float2half(a1 * dr);
  X19[o + 256 + d] = __float2half(a2 * dr);
}

// ---------- hop 2: xs2[r] = (1/deg[r]) * sum_c xs1[c] - xs0[r]
// 192 threads; thread t owns elems {2t, 2t+1}; half2 gather
__global__ void __launch_bounds__(192)
k_spmm2(const float* __restrict__ x_sig, const float* __restrict__ scales,
        __half* __restrict__ X19,
        const int* __restrict__ off, const int* __restrict__ csr_col,
        const float* __restrict__ deg) {
  int r = blockIdx.x;
  int t = threadIdx.x;              // 0..191
  __shared__ int scol[192];
  int start = off[r], end = off[r + 1];
  float acc0 = 0.f, acc1 = 0.f;
  for (int b = start; b < end; b += 192) {
    int len = min(end - b, 192);
    if (t < len) scol[t] = csr_col[b + t];
    __syncthreads();
    for (int j = 0; j < len; ++j) {
      __half2 h = *reinterpret_cast<const __half2*>(
          X19 + (size_t)scol[j] * X19_STRIDE + 2 * t);
      float2 f = __half22float2(h);
      acc0 += f.x; acc1 += f.y;
    }
    __syncthreads();
  }
  float dr = 1.0f / deg[r];
  int e0 = 2 * t;
  int k = e0 >> 7, dd = e0 & 127;
  float2 xv = *reinterpret_cast<const float2*>(x_sig + (size_t)r * D128 + dd);
  float sk = (k == 0) ? 1.0f : ((k == 1) ? scales[2 * r] : scales[2 * r + 1]);
  __half2 o;
  o.x = __float2half(acc0 * dr - xv.x * sk);
  o.y = __float2half(acc1 * dr - xv.y * sk);
  *reinterpret_cast<__half2*>(X19 + (size_t)r * X19_STRIDE + 384 + e0) = o;
}

// ---------- edge gram via MFMA: G(16x16) = A(16x128) B^T, rows 0-8 live ----------
// 4 edges per 256-thread block, one wave per edge. Operands loaded global->reg
// in fragment layout (lane: row=l&15, kgroup=l>>4; 8 contiguous fp16 per chunk).
__global__ void __launch_bounds__(256)
k_edge(const float* __restrict__ x_sig, const float* __restrict__ scales,
       const __half* __restrict__ X19, const int* __restrict__ edge,
       float* __restrict__ out, int E) {
  __shared__ float Gs[4][81];
  int w    = threadIdx.x >> 6;
  int lane = threadIdx.x & 63;
  int e = blockIdx.x * 4 + w;
  int row = lane & 15;      // A row / B col (feature-slice index)
  int kg  = lane >> 4;      // k-group within the 32-wide chunk

  f32x4 acc = {0.f, 0.f, 0.f, 0.f};
  if (e < E) {
    int u = edge[e];
    int v = edge[E + e];
    float su = (row == 1) ? scales[2 * u] : ((row == 2) ? scales[2 * u + 1] : 1.0f);
    float sv = (row == 1) ? scales[2 * v] : ((row == 2) ? scales[2 * v + 1] : 1.0f);
    const float*  xu = x_sig + (size_t)u * D128;
    const float*  xv = x_sig + (size_t)v * D128;
    const __half* Xu = X19 + (size_t)u * X19_STRIDE;
    const __half* Xv = X19 + (size_t)v * X19_STRIDE;
    #pragma unroll
    for (int c = 0; c < 4; ++c) {
      int koff = c * 32 + kg * 8;
      f16x8 a, b;
      if (row >= 9) {
        #pragma unroll
        for (int j = 0; j < 8; ++j) { a[j] = (_Float16)0.0f; b[j] = (_Float16)0.0f; }
      } else if (row < 3) {
        #pragma unroll
        for (int j = 0; j < 8; ++j) a[j] = (_Float16)(xu[koff + j] * su);
        #pragma unroll
        for (int j = 0; j < 8; ++j) b[j] = (_Float16)(xv[koff + j] * sv);
      } else {
        a = *reinterpret_cast<const f16x8*>(Xu + (row - 3) * D128 + koff);
        b = *reinterpret_cast<const f16x8*>(Xv + (row - 3) * D128 + koff);
      }
      acc = __builtin_amdgcn_mfma_f32_16x16x32_f16(a, b, acc, 0, 0, 0);
    }
    // C frag: col = lane&15, row = kg*4 + j  (dtype-independent layout)
    #pragma unroll
    for (int j = 0; j < 4; ++j) {
      int r = kg * 4 + j;
      if (r < 9 && row < 9) Gs[w][r * 9 + row] = acc[j];
    }
  }
  __syncthreads();
  if (e < E) {
    for (int t = lane; t < 81; t += 64) {
      int k = t / 9, l = t % 9;
      out[(size_t)e * 81 + t] = Gs[w][t] + Gs[w][l * 9 + k];
    }
  }
}

extern "C" void kernel_launch(void* const* d_in, const int* in_sizes, int n_in,
                              void* d_out, int out_size, void* d_ws, size_t ws_size,
                              hipStream_t stream) {
  const int*   edge    = (const int*)d_in[0];
  const int*   adj_row = (const int*)d_in[1];
  const int*   adj_col = (const int*)d_in[2];
  const float* deg     = (const float*)d_in[3];
  const float* x_sig   = (const float*)d_in[4];
  float* out = (float*)d_out;   // reference output dtype is float32

  const int E = in_sizes[0] / 2;
  const int M = in_sizes[1];
  const int N = in_sizes[3];

  // workspace layout: X19 (fp16), scales (f32), off/cursor/csr_col (i32)
  size_t x19_elems = (size_t)N * X19_STRIDE;                      // fp16
  size_t need = x19_elems * 2
              + (2 * (size_t)N) * 4                               // scales
              + ((size_t)(N + 1) + (size_t)N + (size_t)M) * 4;    // off, cursor, csr_col
  if (ws_size < need) return;  // diagnostic: all-zero output => absmax ~2.03125

  __half* X19   = (__half*)d_ws;
  float* scales = (float*)(X19 + x19_elems);
  int* off      = (int*)(scales + 2 * (size_t)N);
  int* cursor   = off + (N + 1);
  int* csr_col  = cursor + N;

  hipMemsetAsync(cursor, 0, (size_t)N * sizeof(int), stream);

  k_scales<<<(N + 255) / 256, 256, 0, stream>>>(deg, scales, N);
  k_hist<<<(M + 255) / 256, 256, 0, stream>>>(adj_row, cursor, M);
  k_scan<<<1, 1024, 0, stream>>>(cursor, off, cursor, N);
  k_scatter<<<(M + 255) / 256, 256, 0, stream>>>(adj_row, adj_col, cursor, csr_col, M);

  k_spmm1<<<N, D128, 0, stream>>>(x_sig, scales, X19, off, csr_col, deg);
  k_spmm2<<<N, 192, 0, stream>>>(x_sig, scales, X19, off, csr_col, deg);

  k_edge<<<(E + 3) / 4, 256, 0, stream>>>(x_sig, scales, X19, edge, out, E);
}

// Round 13
// 807.251 us; speedup vs baseline: 1.4841x; 1.0612x over previous
//
#include <hip/hip_runtime.h>
#include <hip/hip_fp16.h>

#define D128 128
#define X19_STRIDE 768            // xs1 (384) + xs2 (384) fp16 elems per node

typedef __attribute__((ext_vector_type(8))) _Float16 f16x8;
typedef __attribute__((ext_vector_type(4))) float    f32x4;

// ---------- scales[n] = {rsqrt(deg), rsqrt(1+log(deg))} ----------
__global__ void k_scales(const float* __restrict__ deg, float* __restrict__ scales, int N) {
  int n = blockIdx.x * blockDim.x + threadIdx.x;
  if (n >= N) return;
  float dg = deg[n];
  scales[2 * n]     = rsqrtf(dg);
  scales[2 * n + 1] = rsqrtf(1.0f + logf(dg));
}

// ---------- CSR build ----------
__global__ void k_hist(const int* __restrict__ row, int* __restrict__ cnt, int M) {
  int i = blockIdx.x * blockDim.x + threadIdx.x;
  if (i < M) atomicAdd(&cnt[row[i]], 1);
}

// multi-block scan, pass 1: per-1024-chunk sums
__global__ void __launch_bounds__(256)
k_blocksum(const int* __restrict__ cnt, int* __restrict__ bsum, int n) {
  __shared__ int ws[4];
  int base = blockIdx.x * 1024;
  int t = threadIdx.x;
  int s = 0;
  for (int j = t; j < 1024; j += 256) {
    int i = base + j;
    if (i < n) s += cnt[i];
  }
  #pragma unroll
  for (int d = 32; d >= 1; d >>= 1) s += __shfl_down(s, d);
  if ((t & 63) == 0) ws[t >> 6] = s;
  __syncthreads();
  if (t == 0) bsum[blockIdx.x] = ws[0] + ws[1] + ws[2] + ws[3];
}

// pass 2: serial exclusive scan of the (tiny) chunk sums; off[n] = total
__global__ void k_scan_bsums(const int* __restrict__ bsum, int* __restrict__ bpre,
                             int* __restrict__ off, int nb, int n) {
  if (threadIdx.x == 0 && blockIdx.x == 0) {
    int run = 0;
    for (int b = 0; b < nb; ++b) { bpre[b] = run; run += bsum[b]; }
    off[n] = run;
  }
}

// pass 3: per-chunk exclusive scan + chunk prefix -> off[i], cursor[i]
__global__ void __launch_bounds__(1024)
k_scan_apply(const int* __restrict__ cnt, const int* __restrict__ bpre,
             int* __restrict__ off, int* __restrict__ cursor, int n) {
  __shared__ int warp_sums[16];
  int i = blockIdx.x * 1024 + threadIdx.x;
  int lane = threadIdx.x & 63;
  int wid  = threadIdx.x >> 6;
  int v = (i < n) ? cnt[i] : 0;
  int s = v;
  #pragma unroll
  for (int d = 1; d < 64; d <<= 1) {
    int t = __shfl_up(s, d);
    if (lane >= d) s += t;
  }
  if (lane == 63) warp_sums[wid] = s;
  __syncthreads();
  if (threadIdx.x < 16) {
    int ws = warp_sums[threadIdx.x];
    #pragma unroll
    for (int d = 1; d < 16; d <<= 1) {
      int t = __shfl_up(ws, d);
      if ((int)threadIdx.x >= d) ws += t;
    }
    warp_sums[threadIdx.x] = ws;
  }
  __syncthreads();
  int excl = (s - v) + (wid > 0 ? warp_sums[wid - 1] : 0) + bpre[blockIdx.x];
  if (i < n) { off[i] = excl; cursor[i] = excl; }
}

__global__ void k_scatter(const int* __restrict__ row, const int* __restrict__ col,
                          int* __restrict__ cursor, int* __restrict__ csr_col, int M) {
  int i = blockIdx.x * blockDim.x + threadIdx.x;
  if (i < M) {
    int r = row[i];
    int pos = atomicAdd(&cursor[r], 1);
    csr_col[pos] = col[i];
  }
}

// ---------- hop 1: xs1[r] = (1/deg[r]) * sum_c [x_sig[c] | x_sig[c]*s1(c) | x_sig[c]*s2(c)]
__global__ void __launch_bounds__(D128)
k_spmm1(const float* __restrict__ x_sig, const float* __restrict__ scales,
        __half* __restrict__ X19,
        const int* __restrict__ off, const int* __restrict__ csr_col,
        const float* __restrict__ deg) {
  int r = blockIdx.x;
  int d = threadIdx.x;
  __shared__ int scol[D128];
  int start = off[r], end = off[r + 1];
  float a0 = 0.f, a1 = 0.f, a2 = 0.f;
  for (int b = start; b < end; b += D128) {
    int len = min(end - b, D128);
    if (d < len) scol[d] = csr_col[b + d];
    __syncthreads();
    for (int j = 0; j < len; ++j) {
      int c = scol[j];
      float v  = x_sig[(size_t)c * D128 + d];
      float s1 = scales[2 * c];
      float s2 = scales[2 * c + 1];
      a0 += v;
      a1 += v * s1;
      a2 += v * s2;
    }
    __syncthreads();
  }
  float dr = 1.0f / deg[r];
  size_t o = (size_t)r * X19_STRIDE;
  X19[o + d]       = __float2half(a0 * dr);
  X19[o + 128 + d] = __float2half(a1 * dr);
  X19[o + 256 + d] = __float2half(a2 * dr);
}

// ---------- hop 2: xs2[r] = (1/deg[r]) * sum_c xs1[c] - xs0[r]
// 192 threads; thread t owns elems {2t, 2t+1}; half2 gather
__global__ void __launch_bounds__(192)
k_spmm2(const float* __restrict__ x_sig, const float* __restrict__ scales,
        __half* __restrict__ X19,
        const int* __restrict__ off, const int* __restrict__ csr_col,
        const float* __restrict__ deg) {
  int r = blockIdx.x;
  int t = threadIdx.x;              // 0..191
  __shared__ int scol[192];
  int start = off[r], end = off[r + 1];
  float acc0 = 0.f, acc1 = 0.f;
  for (int b = start; b < end; b += 192) {
    int len = min(end - b, 192);
    if (t < len) scol[t] = csr_col[b + t];
    __syncthreads();
    for (int j = 0; j < len; ++j) {
      __half2 h = *reinterpret_cast<const __half2*>(
          X19 + (size_t)scol[j] * X19_STRIDE + 2 * t);
      float2 f = __half22float2(h);
      acc0 += f.x; acc1 += f.y;
    }
    __syncthreads();
  }
  float dr = 1.0f / deg[r];
  int e0 = 2 * t;
  int k = e0 >> 7, dd = e0 & 127;
  float2 xv = *reinterpret_cast<const float2*>(x_sig + (size_t)r * D128 + dd);
  float sk = (k == 0) ? 1.0f : ((k == 1) ? scales[2 * r] : scales[2 * r + 1]);
  __half2 o;
  o.x = __float2half(acc0 * dr - xv.x * sk);
  o.y = __float2half(acc1 * dr - xv.y * sk);
  *reinterpret_cast<__half2*>(X19 + (size_t)r * X19_STRIDE + 384 + e0) = o;
}

// ---------- edge gram via MFMA: G(16x16) = A(16x128) B^T, rows 0-8 live ----------
// 4 edges per 256-thread block, one wave per edge. All 4 k-chunks of A and B
// are loaded into registers BEFORE the MFMA chain (ILP over the L2/L3 latency).
__global__ void __launch_bounds__(256)
k_edge(const float* __restrict__ x_sig, const float* __restrict__ scales,
       const __half* __restrict__ X19, const int* __restrict__ edge,
       float* __restrict__ out, int E) {
  __shared__ float Gs[4][81];
  int w    = threadIdx.x >> 6;
  int lane = threadIdx.x & 63;
  int e = blockIdx.x * 4 + w;
  int row = lane & 15;      // A row / B col (feature-slice index)
  int kg  = lane >> 4;      // k-group within the 32-wide chunk

  f32x4 acc = {0.f, 0.f, 0.f, 0.f};
  if (e < E) {
    int u = edge[e];
    int v = edge[E + e];
    float su = (row == 1) ? scales[2 * u] : ((row == 2) ? scales[2 * u + 1] : 1.0f);
    float sv = (row == 1) ? scales[2 * v] : ((row == 2) ? scales[2 * v + 1] : 1.0f);
    const float*  xu = x_sig + (size_t)u * D128;
    const float*  xv = x_sig + (size_t)v * D128;
    const __half* Xu = X19 + (size_t)u * X19_STRIDE;
    const __half* Xv = X19 + (size_t)v * X19_STRIDE;

    f16x8 a[4], b[4];
    if (row >= 9) {
      #pragma unroll
      for (int c = 0; c < 4; ++c)
        #pragma unroll
        for (int j = 0; j < 8; ++j) { a[c][j] = (_Float16)0.0f; b[c][j] = (_Float16)0.0f; }
    } else if (row < 3) {
      #pragma unroll
      for (int c = 0; c < 4; ++c) {
        int koff = c * 32 + kg * 8;
        float4 u0 = *reinterpret_cast<const float4*>(xu + koff);
        float4 u1 = *reinterpret_cast<const float4*>(xu + koff + 4);
        float4 v0 = *reinterpret_cast<const float4*>(xv + koff);
        float4 v1 = *reinterpret_cast<const float4*>(xv + koff + 4);
        a[c][0] = (_Float16)(u0.x * su); a[c][1] = (_Float16)(u0.y * su);
        a[c][2] = (_Float16)(u0.z * su); a[c][3] = (_Float16)(u0.w * su);
        a[c][4] = (_Float16)(u1.x * su); a[c][5] = (_Float16)(u1.y * su);
        a[c][6] = (_Float16)(u1.z * su); a[c][7] = (_Float16)(u1.w * su);
        b[c][0] = (_Float16)(v0.x * sv); b[c][1] = (_Float16)(v0.y * sv);
        b[c][2] = (_Float16)(v0.z * sv); b[c][3] = (_Float16)(v0.w * sv);
        b[c][4] = (_Float16)(v1.x * sv); b[c][5] = (_Float16)(v1.y * sv);
        b[c][6] = (_Float16)(v1.z * sv); b[c][7] = (_Float16)(v1.w * sv);
      }
    } else {
      const __half* pu = Xu + (row - 3) * D128;
      const __half* pv = Xv + (row - 3) * D128;
      #pragma unroll
      for (int c = 0; c < 4; ++c) {
        int koff = c * 32 + kg * 8;
        a[c] = *reinterpret_cast<const f16x8*>(pu + koff);
        b[c] = *reinterpret_cast<const f16x8*>(pv + koff);
      }
    }
    #pragma unroll
    for (int c = 0; c < 4; ++c)
      acc = __builtin_amdgcn_mfma_f32_16x16x32_f16(a[c], b[c], acc, 0, 0, 0);

    // C frag: col = lane&15, row = kg*4 + j  (dtype-independent layout)
    #pragma unroll
    for (int j = 0; j < 4; ++j) {
      int r = kg * 4 + j;
      if (r < 9 && row < 9) Gs[w][r * 9 + row] = acc[j];
    }
  }
  __syncthreads();
  if (e < E) {
    for (int t = lane; t < 81; t += 64) {
      int k = t / 9, l = t % 9;
      out[(size_t)e * 81 + t] = Gs[w][t] + Gs[w][l * 9 + k];
    }
  }
}

extern "C" void kernel_launch(void* const* d_in, const int* in_sizes, int n_in,
                              void* d_out, int out_size, void* d_ws, size_t ws_size,
                              hipStream_t stream) {
  const int*   edge    = (const int*)d_in[0];
  const int*   adj_row = (const int*)d_in[1];
  const int*   adj_col = (const int*)d_in[2];
  const float* deg     = (const float*)d_in[3];
  const float* x_sig   = (const float*)d_in[4];
  float* out = (float*)d_out;   // reference output dtype is float32

  const int E = in_sizes[0] / 2;
  const int M = in_sizes[1];
  const int N = in_sizes[3];
  const int NCHUNK = (N + 1023) / 1024;

  // workspace layout: X19 (fp16), scales (f32), off/cursor/csr_col/bsum/bpre (i32)
  size_t x19_elems = (size_t)N * X19_STRIDE;                      // fp16
  size_t need = x19_elems * 2
              + (2 * (size_t)N) * 4                               // scales
              + ((size_t)(N + 1) + (size_t)N + (size_t)M) * 4     // off, cursor, csr_col
              + 2 * (size_t)NCHUNK * 4;                           // bsum, bpre
  if (ws_size < need) return;  // diagnostic: all-zero output => absmax ~2.03125

  __half* X19   = (__half*)d_ws;
  float* scales = (float*)(X19 + x19_elems);
  int* off      = (int*)(scales + 2 * (size_t)N);
  int* cursor   = off + (N + 1);
  int* csr_col  = cursor + N;
  int* bsum     = csr_col + M;
  int* bpre     = bsum + NCHUNK;

  hipMemsetAsync(cursor, 0, (size_t)N * sizeof(int), stream);

  k_scales<<<(N + 255) / 256, 256, 0, stream>>>(deg, scales, N);
  k_hist<<<(M + 255) / 256, 256, 0, stream>>>(adj_row, cursor, M);
  k_blocksum<<<NCHUNK, 256, 0, stream>>>(cursor, bsum, N);
  k_scan_bsums<<<1, 64, 0, stream>>>(bsum, bpre, off, NCHUNK, N);
  k_scan_apply<<<NCHUNK, 1024, 0, stream>>>(cursor, bpre, off, cursor, N);
  k_scatter<<<(M + 255) / 256, 256, 0, stream>>>(adj_row, adj_col, cursor, csr_col, M);

  k_spmm1<<<N, D128, 0, stream>>>(x_sig, scales, X19, off, csr_col, deg);
  k_spmm2<<<N, 192, 0, stream>>>(x_sig, scales, X19, off, csr_col, deg);

  k_edge<<<(E + 3) / 4, 256, 0, stream>>>(x_sig, scales, X19, edge, out, E);
}

// Round 14
// 759.249 us; speedup vs baseline: 1.5779x; 1.0632x over previous
//
#include <hip/hip_runtime.h>
#include <hip/hip_fp16.h>

#define D128 128
#define X19_STRIDE 768            // 6 propagated slices (xs1,xs2) fp16 per node

typedef __attribute__((ext_vector_type(8))) _Float16 f16x8;
typedef __attribute__((ext_vector_type(4))) float    f32x4;

// ---------- scales[n] = {rsqrt(deg), rsqrt(1+log(deg))} ----------
__global__ void k_scales(const float* __restrict__ deg, float* __restrict__ scales, int N) {
  int n = blockIdx.x * blockDim.x + threadIdx.x;
  if (n >= N) return;
  float dg = deg[n];
  scales[2 * n]     = rsqrtf(dg);
  scales[2 * n + 1] = rsqrtf(1.0f + logf(dg));
}

// ---------- CSR build ----------
__global__ void k_hist(const int* __restrict__ row, int* __restrict__ cnt, int M) {
  int i = blockIdx.x * blockDim.x + threadIdx.x;
  if (i < M) atomicAdd(&cnt[row[i]], 1);
}

__global__ void __launch_bounds__(256)
k_blocksum(const int* __restrict__ cnt, int* __restrict__ bsum, int n) {
  __shared__ int ws[4];
  int base = blockIdx.x * 1024;
  int t = threadIdx.x;
  int s = 0;
  for (int j = t; j < 1024; j += 256) {
    int i = base + j;
    if (i < n) s += cnt[i];
  }
  #pragma unroll
  for (int d = 32; d >= 1; d >>= 1) s += __shfl_down(s, d);
  if ((t & 63) == 0) ws[t >> 6] = s;
  __syncthreads();
  if (t == 0) bsum[blockIdx.x] = ws[0] + ws[1] + ws[2] + ws[3];
}

__global__ void k_scan_bsums(const int* __restrict__ bsum, int* __restrict__ bpre,
                             int* __restrict__ off, int nb, int n) {
  if (threadIdx.x == 0 && blockIdx.x == 0) {
    int run = 0;
    for (int b = 0; b < nb; ++b) { bpre[b] = run; run += bsum[b]; }
    off[n] = run;
  }
}

__global__ void __launch_bounds__(1024)
k_scan_apply(const int* __restrict__ cnt, const int* __restrict__ bpre,
             int* __restrict__ off, int* __restrict__ cursor, int n) {
  __shared__ int warp_sums[16];
  int i = blockIdx.x * 1024 + threadIdx.x;
  int lane = threadIdx.x & 63;
  int wid  = threadIdx.x >> 6;
  int v = (i < n) ? cnt[i] : 0;
  int s = v;
  #pragma unroll
  for (int d = 1; d < 64; d <<= 1) {
    int t = __shfl_up(s, d);
    if (lane >= d) s += t;
  }
  if (lane == 63) warp_sums[wid] = s;
  __syncthreads();
  if (threadIdx.x < 16) {
    int ws = warp_sums[threadIdx.x];
    #pragma unroll
    for (int d = 1; d < 16; d <<= 1) {
      int t = __shfl_up(ws, d);
      if ((int)threadIdx.x >= d) ws += t;
    }
    warp_sums[threadIdx.x] = ws;
  }
  __syncthreads();
  int excl = (s - v) + (wid > 0 ? warp_sums[wid - 1] : 0) + bpre[blockIdx.x];
  if (i < n) { off[i] = excl; cursor[i] = excl; }
}

__global__ void k_scatter(const int* __restrict__ row, const int* __restrict__ col,
                          int* __restrict__ cursor, int* __restrict__ csr_col, int M) {
  int i = blockIdx.x * blockDim.x + threadIdx.x;
  if (i < M) {
    int r = row[i];
    int pos = atomicAdd(&cursor[r], 1);
    csr_col[pos] = col[i];
  }
}

// ---------- hop 1: wave per row; lane owns dims {2l, 2l+1}; shfl-broadcast cols ----------
__global__ void __launch_bounds__(256)
k_spmm1(const float* __restrict__ x_sig, const float* __restrict__ scales,
        __half* __restrict__ X19,
        const int* __restrict__ off, const int* __restrict__ csr_col,
        const float* __restrict__ deg, int N) {
  int r = blockIdx.x * 4 + (threadIdx.x >> 6);
  if (r >= N) return;
  int lane = threadIdx.x & 63;
  int d0 = lane * 2;
  int start = off[r], end = off[r + 1];
  float a0x = 0.f, a0y = 0.f, a1x = 0.f, a1y = 0.f, a2x = 0.f, a2y = 0.f;
  for (int b = start; b < end; b += 64) {
    int len = min(end - b, 64);
    int ci = (lane < len) ? csr_col[b + lane] : 0;
    for (int j = 0; j < len; ++j) {
      int c = __shfl(ci, j);
      float2 v = *reinterpret_cast<const float2*>(x_sig + (size_t)c * D128 + d0);
      float2 s = *reinterpret_cast<const float2*>(scales + 2 * c);
      a0x += v.x;        a0y += v.y;
      a1x += v.x * s.x;  a1y += v.y * s.x;
      a2x += v.x * s.y;  a2y += v.y * s.y;
    }
  }
  float dr = 1.0f / deg[r];
  __half* o = X19 + (size_t)r * X19_STRIDE + d0;
  *reinterpret_cast<__half2*>(o)       = __floats2half2_rn(a0x * dr, a0y * dr);
  *reinterpret_cast<__half2*>(o + 128) = __floats2half2_rn(a1x * dr, a1y * dr);
  *reinterpret_cast<__half2*>(o + 256) = __floats2half2_rn(a2x * dr, a2y * dr);
}

// ---------- hop 2: wave per row; lane owns 6 dims (3 half2 at +0/+128/+256) ----------
__global__ void __launch_bounds__(256)
k_spmm2(const float* __restrict__ x_sig, const float* __restrict__ scales,
        __half* __restrict__ X19,
        const int* __restrict__ off, const int* __restrict__ csr_col,
        const float* __restrict__ deg, int N) {
  int r = blockIdx.x * 4 + (threadIdx.x >> 6);
  if (r >= N) return;
  int lane = threadIdx.x & 63;
  int d0 = lane * 2;
  int start = off[r], end = off[r + 1];
  float s0x = 0.f, s0y = 0.f, s1x = 0.f, s1y = 0.f, s2x = 0.f, s2y = 0.f;
  for (int b = start; b < end; b += 64) {
    int len = min(end - b, 64);
    int ci = (lane < len) ? csr_col[b + lane] : 0;
    for (int j = 0; j < len; ++j) {
      int c = __shfl(ci, j);
      const __half* base = X19 + (size_t)c * X19_STRIDE + d0;
      float2 v0 = __half22float2(*reinterpret_cast<const __half2*>(base));
      float2 v1 = __half22float2(*reinterpret_cast<const __half2*>(base + 128));
      float2 v2 = __half22float2(*reinterpret_cast<const __half2*>(base + 256));
      s0x += v0.x; s0y += v0.y;
      s1x += v1.x; s1y += v1.y;
      s2x += v2.x; s2y += v2.y;
    }
  }
  float dr = 1.0f / deg[r];
  float2 xv = *reinterpret_cast<const float2*>(x_sig + (size_t)r * D128 + d0);
  float2 sc = *reinterpret_cast<const float2*>(scales + 2 * r);
  __half* o = X19 + (size_t)r * X19_STRIDE + 384 + d0;
  *reinterpret_cast<__half2*>(o)       = __floats2half2_rn(s0x * dr - xv.x,        s0y * dr - xv.y);
  *reinterpret_cast<__half2*>(o + 128) = __floats2half2_rn(s1x * dr - xv.x * sc.x, s1y * dr - xv.y * sc.x);
  *reinterpret_cast<__half2*>(o + 256) = __floats2half2_rn(s2x * dr - xv.x * sc.y, s2y * dr - xv.y * sc.y);
}

// ---------- edge gram via MFMA: 7x7 gram per edge, 2 edges per wave ----------
// A rows 0-6 = edge0 u-features [x_sig | 6 X19 rows]; rows 8-14 = edge1 u-features.
// B likewise with v. C diag blocks -> G7 per edge; 9x9 expansion in epilogue:
// out[k][l] = ak(u)*bl(v)*G7[k'][l'] + al(u)*bk(v)*G7[l'][k'].
__global__ void __launch_bounds__(256)
k_edge(const float* __restrict__ x_sig, const float* __restrict__ scales,
       const __half* __restrict__ X19, const int* __restrict__ edge,
       float* __restrict__ out, int E) {
  __shared__ float Gs[4][2][49];
  int w    = threadIdx.x >> 6;
  int lane = threadIdx.x & 63;
  long e0 = ((long)blockIdx.x * 4 + w) * 2;
  int row = lane & 15;          // A-row / B-row index (0..15)
  int kg  = lane >> 4;          // k-group
  int f   = min(row & 7, 6);    // feature id 0..6 (rows 7/15 clamp-dup row 6)
  long ea = e0 + ((row >> 3) & 1);
  bool va = ea < E;
  int u = va ? edge[ea] : 0;
  int v = va ? edge[E + ea] : 0;
  const float*  xu = x_sig + (size_t)u * D128;
  const float*  xv = x_sig + (size_t)v * D128;
  const __half* Xu = X19 + (size_t)u * X19_STRIDE + (f - 1) * D128;
  const __half* Xv = X19 + (size_t)v * X19_STRIDE + (f - 1) * D128;

  f32x4 acc = {0.f, 0.f, 0.f, 0.f};
  #pragma unroll
  for (int c = 0; c < 4; ++c) {
    int koff = c * 32 + kg * 8;
    f16x8 a, b;
    if (f == 0) {
      float4 u0 = *reinterpret_cast<const float4*>(xu + koff);
      float4 u1 = *reinterpret_cast<const float4*>(xu + koff + 4);
      float4 v0 = *reinterpret_cast<const float4*>(xv + koff);
      float4 v1 = *reinterpret_cast<const float4*>(xv + koff + 4);
      a[0] = (_Float16)u0.x; a[1] = (_Float16)u0.y; a[2] = (_Float16)u0.z; a[3] = (_Float16)u0.w;
      a[4] = (_Float16)u1.x; a[5] = (_Float16)u1.y; a[6] = (_Float16)u1.z; a[7] = (_Float16)u1.w;
      b[0] = (_Float16)v0.x; b[1] = (_Float16)v0.y; b[2] = (_Float16)v0.z; b[3] = (_Float16)v0.w;
      b[4] = (_Float16)v1.x; b[5] = (_Float16)v1.y; b[6] = (_Float16)v1.z; b[7] = (_Float16)v1.w;
    } else {
      a = *reinterpret_cast<const f16x8*>(Xu + koff);
      b = *reinterpret_cast<const f16x8*>(Xv + koff);
    }
    acc = __builtin_amdgcn_mfma_f32_16x16x32_f16(a, b, acc, 0, 0, 0);
  }
  // C frag: ccol = lane&15, crow = kg*4 + j
  #pragma unroll
  for (int j = 0; j < 4; ++j) {
    int cr = kg * 4 + j;
    int cc = row;
    if (cr < 7 && cc < 7)                       Gs[w][0][cr * 7 + cc] = acc[j];
    else if (cr >= 8 && cr < 15 && cc >= 8 && cc < 15)
                                                Gs[w][1][(cr - 8) * 7 + (cc - 8)] = acc[j];
  }
  __syncthreads();
  #pragma unroll
  for (int ee = 0; ee < 2; ++ee) {
    long e = e0 + ee;
    if (e >= E) break;
    int uu = edge[e], vv = edge[E + e];
    float su1 = scales[2 * uu], su2 = scales[2 * uu + 1];
    float sv1 = scales[2 * vv], sv2 = scales[2 * vv + 1];
    const float* G = Gs[w][ee];
    for (int t = lane; t < 81; t += 64) {
      int k = t / 9, l = t % 9;
      int kp = (k < 3) ? 0 : k - 2;
      int lp = (l < 3) ? 0 : l - 2;
      float ak = (k == 1) ? su1 : ((k == 2) ? su2 : 1.f);
      float al = (l == 1) ? su1 : ((l == 2) ? su2 : 1.f);
      float bk = (k == 1) ? sv1 : ((k == 2) ? sv2 : 1.f);
      float bl = (l == 1) ? sv1 : ((l == 2) ? sv2 : 1.f);
      out[(size_t)e * 81 + t] = ak * bl * G[kp * 7 + lp] + al * bk * G[lp * 7 + kp];
    }
  }
}

extern "C" void kernel_launch(void* const* d_in, const int* in_sizes, int n_in,
                              void* d_out, int out_size, void* d_ws, size_t ws_size,
                              hipStream_t stream) {
  const int*   edge    = (const int*)d_in[0];
  const int*   adj_row = (const int*)d_in[1];
  const int*   adj_col = (const int*)d_in[2];
  const float* deg     = (const float*)d_in[3];
  const float* x_sig   = (const float*)d_in[4];
  float* out = (float*)d_out;   // reference output dtype is float32

  const int E = in_sizes[0] / 2;
  const int M = in_sizes[1];
  const int N = in_sizes[3];
  const int NCHUNK = (N + 1023) / 1024;

  // workspace layout: X19 (fp16), scales (f32), off/cursor/csr_col/bsum/bpre (i32)
  size_t x19_elems = (size_t)N * X19_STRIDE;                      // fp16
  size_t need = x19_elems * 2
              + (2 * (size_t)N) * 4
              + ((size_t)(N + 1) + (size_t)N + (size_t)M) * 4
              + 2 * (size_t)NCHUNK * 4;
  if (ws_size < need) return;  // diagnostic: all-zero output => absmax ~2.03125

  __half* X19   = (__half*)d_ws;
  float* scales = (float*)(X19 + x19_elems);
  int* off      = (int*)(scales + 2 * (size_t)N);
  int* cursor   = off + (N + 1);
  int* csr_col  = cursor + N;
  int* bsum     = csr_col + M;
  int* bpre     = bsum + NCHUNK;

  hipMemsetAsync(cursor, 0, (size_t)N * sizeof(int), stream);

  k_scales<<<(N + 255) / 256, 256, 0, stream>>>(deg, scales, N);
  k_hist<<<(M + 255) / 256, 256, 0, stream>>>(adj_row, cursor, M);
  k_blocksum<<<NCHUNK, 256, 0, stream>>>(cursor, bsum, N);
  k_scan_bsums<<<1, 64, 0, stream>>>(bsum, bpre, off, NCHUNK, N);
  k_scan_apply<<<NCHUNK, 1024, 0, stream>>>(cursor, bpre, off, cursor, N);
  k_scatter<<<(M + 255) / 256, 256, 0, stream>>>(adj_row, adj_col, cursor, csr_col, M);

  k_spmm1<<<(N + 3) / 4, 256, 0, stream>>>(x_sig, scales, X19, off, csr_col, deg, N);
  k_spmm2<<<(N + 3) / 4, 256, 0, stream>>>(x_sig, scales, X19, off, csr_col, deg, N);

  k_edge<<<(E + 7) / 8, 256, 0, stream>>>(x_sig, scales, X19, edge, out, E);
}

// Round 15
// 696.727 us; speedup vs baseline: 1.7195x; 1.0897x over previous
//
#include <hip/hip_runtime.h>
#include <hip/hip_fp16.h>

#define D128 128
#define X19_STRIDE 768            // 6 propagated slices (xs1,xs2) fp16 per node

typedef __attribute__((ext_vector_type(8))) _Float16 f16x8;
typedef __attribute__((ext_vector_type(4))) float    f32x4;

// ---------- scales[n] = {rsqrt(deg), rsqrt(1+log(deg))} ----------
__global__ void k_scales(const float* __restrict__ deg, float* __restrict__ scales, int N) {
  int n = blockIdx.x * blockDim.x + threadIdx.x;
  if (n >= N) return;
  float dg = deg[n];
  scales[2 * n]     = rsqrtf(dg);
  scales[2 * n + 1] = rsqrtf(1.0f + logf(dg));
}

// ---------- optional fp16 copy of x_sig ----------
__global__ void k_xh(const float* __restrict__ x, __half* __restrict__ xh, int total2) {
  int i = blockIdx.x * blockDim.x + threadIdx.x;   // element pair index
  if (i >= total2) return;
  float2 v = *reinterpret_cast<const float2*>(x + 2 * i);
  *reinterpret_cast<__half2*>(xh + 2 * i) = __floats2half2_rn(v.x, v.y);
}

// ---------- CSR build ----------
__global__ void k_hist(const int* __restrict__ row, int* __restrict__ cnt, int M) {
  int i = blockIdx.x * blockDim.x + threadIdx.x;
  if (i < M) atomicAdd(&cnt[row[i]], 1);
}

__global__ void __launch_bounds__(256)
k_blocksum(const int* __restrict__ cnt, int* __restrict__ bsum, int n) {
  __shared__ int ws[4];
  int base = blockIdx.x * 1024;
  int t = threadIdx.x;
  int s = 0;
  for (int j = t; j < 1024; j += 256) {
    int i = base + j;
    if (i < n) s += cnt[i];
  }
  #pragma unroll
  for (int d = 32; d >= 1; d >>= 1) s += __shfl_down(s, d);
  if ((t & 63) == 0) ws[t >> 6] = s;
  __syncthreads();
  if (t == 0) bsum[blockIdx.x] = ws[0] + ws[1] + ws[2] + ws[3];
}

__global__ void k_scan_bsums(const int* __restrict__ bsum, int* __restrict__ bpre,
                             int* __restrict__ off, int nb, int n) {
  if (threadIdx.x == 0 && blockIdx.x == 0) {
    int run = 0;
    for (int b = 0; b < nb; ++b) { bpre[b] = run; run += bsum[b]; }
    off[n] = run;
  }
}

__global__ void __launch_bounds__(1024)
k_scan_apply(const int* __restrict__ cnt, const int* __restrict__ bpre,
             int* __restrict__ off, int* __restrict__ cursor, int n) {
  __shared__ int warp_sums[16];
  int i = blockIdx.x * 1024 + threadIdx.x;
  int lane = threadIdx.x & 63;
  int wid  = threadIdx.x >> 6;
  int v = (i < n) ? cnt[i] : 0;
  int s = v;
  #pragma unroll
  for (int d = 1; d < 64; d <<= 1) {
    int t = __shfl_up(s, d);
    if (lane >= d) s += t;
  }
  if (lane == 63) warp_sums[wid] = s;
  __syncthreads();
  if (threadIdx.x < 16) {
    int ws = warp_sums[threadIdx.x];
    #pragma unroll
    for (int d = 1; d < 16; d <<= 1) {
      int t = __shfl_up(ws, d);
      if ((int)threadIdx.x >= d) ws += t;
    }
    warp_sums[threadIdx.x] = ws;
  }
  __syncthreads();
  int excl = (s - v) + (wid > 0 ? warp_sums[wid - 1] : 0) + bpre[blockIdx.x];
  if (i < n) { off[i] = excl; cursor[i] = excl; }
}

__global__ void k_scatter(const int* __restrict__ row, const int* __restrict__ col,
                          int* __restrict__ cursor, int* __restrict__ csr_col, int M) {
  int i = blockIdx.x * blockDim.x + threadIdx.x;
  if (i < M) {
    int r = row[i];
    int pos = atomicAdd(&cursor[r], 1);
    csr_col[pos] = col[i];
  }
}

// ---------- hop 1: wave per row; lane owns dims {2l,2l+1}; readlane-uniform cols ----------
__global__ void __launch_bounds__(256)
k_spmm1(const float* __restrict__ x_sig, const __half* __restrict__ xh, int use_xh,
        const float* __restrict__ scales, __half* __restrict__ X19,
        const int* __restrict__ off, const int* __restrict__ csr_col,
        const float* __restrict__ deg, int N) {
  int r = blockIdx.x * 4 + (threadIdx.x >> 6);
  if (r >= N) return;
  int lane = threadIdx.x & 63;
  int d0 = lane * 2;
  int start = off[r], end = off[r + 1];
  float a0x = 0.f, a0y = 0.f, a1x = 0.f, a1y = 0.f, a2x = 0.f, a2y = 0.f;
  for (int b = start; b < end; b += 64) {
    int len = min(end - b, 64);
    int ci = (lane < len) ? csr_col[b + lane] : 0;
    if (use_xh) {
      int j = 0;
      for (; j + 2 <= len; j += 2) {
        int c0 = __builtin_amdgcn_readlane(ci, j);
        int c1 = __builtin_amdgcn_readlane(ci, j + 1);
        float2 v0 = __half22float2(*reinterpret_cast<const __half2*>(xh + (size_t)c0 * D128 + d0));
        float2 v1 = __half22float2(*reinterpret_cast<const __half2*>(xh + (size_t)c1 * D128 + d0));
        float2 s0 = *reinterpret_cast<const float2*>(scales + 2 * c0);
        float2 s1 = *reinterpret_cast<const float2*>(scales + 2 * c1);
        a0x += v0.x;        a0y += v0.y;
        a1x += v0.x * s0.x; a1y += v0.y * s0.x;
        a2x += v0.x * s0.y; a2y += v0.y * s0.y;
        a0x += v1.x;        a0y += v1.y;
        a1x += v1.x * s1.x; a1y += v1.y * s1.x;
        a2x += v1.x * s1.y; a2y += v1.y * s1.y;
      }
      if (j < len) {
        int c = __builtin_amdgcn_readlane(ci, j);
        float2 v = __half22float2(*reinterpret_cast<const __half2*>(xh + (size_t)c * D128 + d0));
        float2 s = *reinterpret_cast<const float2*>(scales + 2 * c);
        a0x += v.x;        a0y += v.y;
        a1x += v.x * s.x;  a1y += v.y * s.x;
        a2x += v.x * s.y;  a2y += v.y * s.y;
      }
    } else {
      int j = 0;
      for (; j + 2 <= len; j += 2) {
        int c0 = __builtin_amdgcn_readlane(ci, j);
        int c1 = __builtin_amdgcn_readlane(ci, j + 1);
        float2 v0 = *reinterpret_cast<const float2*>(x_sig + (size_t)c0 * D128 + d0);
        float2 v1 = *reinterpret_cast<const float2*>(x_sig + (size_t)c1 * D128 + d0);
        float2 s0 = *reinterpret_cast<const float2*>(scales + 2 * c0);
        float2 s1 = *reinterpret_cast<const float2*>(scales + 2 * c1);
        a0x += v0.x;        a0y += v0.y;
        a1x += v0.x * s0.x; a1y += v0.y * s0.x;
        a2x += v0.x * s0.y; a2y += v0.y * s0.y;
        a0x += v1.x;        a0y += v1.y;
        a1x += v1.x * s1.x; a1y += v1.y * s1.x;
        a2x += v1.x * s1.y; a2y += v1.y * s1.y;
      }
      if (j < len) {
        int c = __builtin_amdgcn_readlane(ci, j);
        float2 v = *reinterpret_cast<const float2*>(x_sig + (size_t)c * D128 + d0);
        float2 s = *reinterpret_cast<const float2*>(scales + 2 * c);
        a0x += v.x;        a0y += v.y;
        a1x += v.x * s.x;  a1y += v.y * s.x;
        a2x += v.x * s.y;  a2y += v.y * s.y;
      }
    }
  }
  float dr = 1.0f / deg[r];
  __half* o = X19 + (size_t)r * X19_STRIDE + d0;
  *reinterpret_cast<__half2*>(o)       = __floats2half2_rn(a0x * dr, a0y * dr);
  *reinterpret_cast<__half2*>(o + 128) = __floats2half2_rn(a1x * dr, a1y * dr);
  *reinterpret_cast<__half2*>(o + 256) = __floats2half2_rn(a2x * dr, a2y * dr);
}

// ---------- hop 2: wave per row; lane owns dims {2l,2l+1} of each slice ----------
__global__ void __launch_bounds__(256)
k_spmm2(const float* __restrict__ x_sig, const float* __restrict__ scales,
        __half* __restrict__ X19,
        const int* __restrict__ off, const int* __restrict__ csr_col,
        const float* __restrict__ deg, int N) {
  int r = blockIdx.x * 4 + (threadIdx.x >> 6);
  if (r >= N) return;
  int lane = threadIdx.x & 63;
  int d0 = lane * 2;
  int start = off[r], end = off[r + 1];
  float s0x = 0.f, s0y = 0.f, s1x = 0.f, s1y = 0.f, s2x = 0.f, s2y = 0.f;
  for (int b = start; b < end; b += 64) {
    int len = min(end - b, 64);
    int ci = (lane < len) ? csr_col[b + lane] : 0;
    int j = 0;
    for (; j + 2 <= len; j += 2) {
      int c0 = __builtin_amdgcn_readlane(ci, j);
      int c1 = __builtin_amdgcn_readlane(ci, j + 1);
      const __half* p = X19 + (size_t)c0 * X19_STRIDE + d0;
      const __half* q = X19 + (size_t)c1 * X19_STRIDE + d0;
      float2 p0 = __half22float2(*reinterpret_cast<const __half2*>(p));
      float2 p1 = __half22float2(*reinterpret_cast<const __half2*>(p + 128));
      float2 p2 = __half22float2(*reinterpret_cast<const __half2*>(p + 256));
      float2 q0 = __half22float2(*reinterpret_cast<const __half2*>(q));
      float2 q1 = __half22float2(*reinterpret_cast<const __half2*>(q + 128));
      float2 q2 = __half22float2(*reinterpret_cast<const __half2*>(q + 256));
      s0x += p0.x + q0.x; s0y += p0.y + q0.y;
      s1x += p1.x + q1.x; s1y += p1.y + q1.y;
      s2x += p2.x + q2.x; s2y += p2.y + q2.y;
    }
    if (j < len) {
      int c = __builtin_amdgcn_readlane(ci, j);
      const __half* p = X19 + (size_t)c * X19_STRIDE + d0;
      float2 p0 = __half22float2(*reinterpret_cast<const __half2*>(p));
      float2 p1 = __half22float2(*reinterpret_cast<const __half2*>(p + 128));
      float2 p2 = __half22float2(*reinterpret_cast<const __half2*>(p + 256));
      s0x += p0.x; s0y += p0.y;
      s1x += p1.x; s1y += p1.y;
      s2x += p2.x; s2y += p2.y;
    }
  }
  float dr = 1.0f / deg[r];
  float2 xv = *reinterpret_cast<const float2*>(x_sig + (size_t)r * D128 + d0);
  float2 sc = *reinterpret_cast<const float2*>(scales + 2 * r);
  __half* o = X19 + (size_t)r * X19_STRIDE + 384 + d0;
  *reinterpret_cast<__half2*>(o)       = __floats2half2_rn(s0x * dr - xv.x,        s0y * dr - xv.y);
  *reinterpret_cast<__half2*>(o + 128) = __floats2half2_rn(s1x * dr - xv.x * sc.x, s1y * dr - xv.y * sc.x);
  *reinterpret_cast<__half2*>(o + 256) = __floats2half2_rn(s2x * dr - xv.x * sc.y, s2y * dr - xv.y * sc.y);
}

// ---------- edge gram via MFMA: 7x7 gram per edge, 2 edges per wave ----------
__global__ void __launch_bounds__(256)
k_edge(const float* __restrict__ x_sig, const __half* __restrict__ xh, int use_xh,
       const float* __restrict__ scales, const __half* __restrict__ X19,
       const int* __restrict__ edge, float* __restrict__ out, int E) {
  __shared__ float Gs[4][2][49];
  int w    = threadIdx.x >> 6;
  int lane = threadIdx.x & 63;
  long e0 = ((long)blockIdx.x * 4 + w) * 2;
  int row = lane & 15;          // A-row / B-row index (0..15)
  int kg  = lane >> 4;          // k-group
  int f   = min(row & 7, 6);    // feature id 0..6 (rows 7/15 clamp-dup row 6)
  long ea = e0 + ((row >> 3) & 1);
  bool va = ea < E;
  int u = va ? edge[ea] : 0;
  int v = va ? edge[E + ea] : 0;

  f32x4 acc = {0.f, 0.f, 0.f, 0.f};
  if (use_xh) {
    const __half* pa = (f == 0) ? xh + (size_t)u * D128
                                : X19 + (size_t)u * X19_STRIDE + (size_t)(f - 1) * D128;
    const __half* pb = (f == 0) ? xh + (size_t)v * D128
                                : X19 + (size_t)v * X19_STRIDE + (size_t)(f - 1) * D128;
    #pragma unroll
    for (int c = 0; c < 4; ++c) {
      int koff = c * 32 + kg * 8;
      f16x8 a = *reinterpret_cast<const f16x8*>(pa + koff);
      f16x8 b = *reinterpret_cast<const f16x8*>(pb + koff);
      acc = __builtin_amdgcn_mfma_f32_16x16x32_f16(a, b, acc, 0, 0, 0);
    }
  } else {
    const float*  xu = x_sig + (size_t)u * D128;
    const float*  xv = x_sig + (size_t)v * D128;
    const __half* Xu = X19 + (size_t)u * X19_STRIDE;
    const __half* Xv = X19 + (size_t)v * X19_STRIDE;
    #pragma unroll
    for (int c = 0; c < 4; ++c) {
      int koff = c * 32 + kg * 8;
      f16x8 a, b;
      if (f == 0) {
        float4 u0 = *reinterpret_cast<const float4*>(xu + koff);
        float4 u1 = *reinterpret_cast<const float4*>(xu + koff + 4);
        float4 v0 = *reinterpret_cast<const float4*>(xv + koff);
        float4 v1 = *reinterpret_cast<const float4*>(xv + koff + 4);
        a[0] = (_Float16)u0.x; a[1] = (_Float16)u0.y; a[2] = (_Float16)u0.z; a[3] = (_Float16)u0.w;
        a[4] = (_Float16)u1.x; a[5] = (_Float16)u1.y; a[6] = (_Float16)u1.z; a[7] = (_Float16)u1.w;
        b[0] = (_Float16)v0.x; b[1] = (_Float16)v0.y; b[2] = (_Float16)v0.z; b[3] = (_Float16)v0.w;
        b[4] = (_Float16)v1.x; b[5] = (_Float16)v1.y; b[6] = (_Float16)v1.z; b[7] = (_Float16)v1.w;
      } else {
        a = *reinterpret_cast<const f16x8*>(Xu + (f - 1) * D128 + koff);
        b = *reinterpret_cast<const f16x8*>(Xv + (f - 1) * D128 + koff);
      }
      acc = __builtin_amdgcn_mfma_f32_16x16x32_f16(a, b, acc, 0, 0, 0);
    }
  }
  // C frag: ccol = lane&15, crow = kg*4 + j
  #pragma unroll
  for (int j = 0; j < 4; ++j) {
    int cr = kg * 4 + j;
    int cc = row;
    if (cr < 7 && cc < 7)                       Gs[w][0][cr * 7 + cc] = acc[j];
    else if (cr >= 8 && cr < 15 && cc >= 8 && cc < 15)
                                                Gs[w][1][(cr - 8) * 7 + (cc - 8)] = acc[j];
  }
  __syncthreads();
  #pragma unroll
  for (int ee = 0; ee < 2; ++ee) {
    long e = e0 + ee;
    if (e >= E) break;
    int uu = edge[e], vv = edge[E + e];
    float su1 = scales[2 * uu], su2 = scales[2 * uu + 1];
    float sv1 = scales[2 * vv], sv2 = scales[2 * vv + 1];
    const float* G = Gs[w][ee];
    for (int t = lane; t < 81; t += 64) {
      int k = t / 9, l = t % 9;
      int kp = (k < 3) ? 0 : k - 2;
      int lp = (l < 3) ? 0 : l - 2;
      float ak = (k == 1) ? su1 : ((k == 2) ? su2 : 1.f);
      float al = (l == 1) ? su1 : ((l == 2) ? su2 : 1.f);
      float bk = (k == 1) ? sv1 : ((k == 2) ? sv2 : 1.f);
      float bl = (l == 1) ? sv1 : ((l == 2) ? sv2 : 1.f);
      out[(size_t)e * 81 + t] = ak * bl * G[kp * 7 + lp] + al * bk * G[lp * 7 + kp];
    }
  }
}

extern "C" void kernel_launch(void* const* d_in, const int* in_sizes, int n_in,
                              void* d_out, int out_size, void* d_ws, size_t ws_size,
                              hipStream_t stream) {
  const int*   edge    = (const int*)d_in[0];
  const int*   adj_row = (const int*)d_in[1];
  const int*   adj_col = (const int*)d_in[2];
  const float* deg     = (const float*)d_in[3];
  const float* x_sig   = (const float*)d_in[4];
  float* out = (float*)d_out;   // reference output dtype is float32

  const int E = in_sizes[0] / 2;
  const int M = in_sizes[1];
  const int N = in_sizes[3];
  const int NCHUNK = (N + 1023) / 1024;

  // workspace layout: X19 (fp16), scales (f32), off/cursor/csr_col/bsum/bpre (i32), [xh fp16]
  size_t x19_elems = (size_t)N * X19_STRIDE;                      // fp16
  size_t base_need = x19_elems * 2
              + (2 * (size_t)N) * 4
              + ((size_t)(N + 1) + (size_t)N + (size_t)M) * 4
              + 2 * (size_t)NCHUNK * 4;
  if (ws_size < base_need) return;  // diagnostic: all-zero output => absmax ~2.03125

  __half* X19   = (__half*)d_ws;
  float* scales = (float*)(X19 + x19_elems);
  int* off      = (int*)(scales + 2 * (size_t)N);
  int* cursor   = off + (N + 1);
  int* csr_col  = cursor + N;
  int* bsum     = csr_col + M;
  int* bpre     = bsum + NCHUNK;

  size_t xh_off   = (base_need + 255) & ~(size_t)255;
  size_t xh_bytes = (size_t)N * D128 * 2;
  int use_xh = (ws_size >= xh_off + xh_bytes) ? 1 : 0;
  __half* xh = use_xh ? (__half*)((char*)d_ws + xh_off) : (__half*)d_ws;

  hipMemsetAsync(cursor, 0, (size_t)N * sizeof(int), stream);

  k_scales<<<(N + 255) / 256, 256, 0, stream>>>(deg, scales, N);
  if (use_xh)
    k_xh<<<(N * 64 + 255) / 256, 256, 0, stream>>>(x_sig, xh, N * 64);
  k_hist<<<(M + 255) / 256, 256, 0, stream>>>(adj_row, cursor, M);
  k_blocksum<<<NCHUNK, 256, 0, stream>>>(cursor, bsum, N);
  k_scan_bsums<<<1, 64, 0, stream>>>(bsum, bpre, off, NCHUNK, N);
  k_scan_apply<<<NCHUNK, 1024, 0, stream>>>(cursor, bpre, off, cursor, N);
  k_scatter<<<(M + 255) / 256, 256, 0, stream>>>(adj_row, adj_col, cursor, csr_col, M);

  k_spmm1<<<(N + 3) / 4, 256, 0, stream>>>(x_sig, xh, use_xh, scales, X19, off, csr_col, deg, N);
  k_spmm2<<<(N + 3) / 4, 256, 0, stream>>>(x_sig, scales, X19, off, csr_col, deg, N);

  k_edge<<<(E + 7) / 8, 256, 0, stream>>>(x_sig, xh, use_xh, scales, X19, edge, out, E);
}